// Round 8
// baseline (464.726 us; speedup 1.0000x reference)
//
#include <hip/hip_runtime.h>

#define NG 64
#define HIDW 200
#define DIN 128
#define KPAD 224
#define POOL_NC 8

typedef _Float16 half4_t __attribute__((ext_vector_type(4)));
typedef _Float16 half8_t __attribute__((ext_vector_type(8)));
typedef float floatx4 __attribute__((ext_vector_type(4)));

// ---------------- build: degree count + graph-start table (fused) ----------------

__global__ void build_kernel(const int* __restrict__ dst, int* __restrict__ counts,
                             const int* __restrict__ batch, int* __restrict__ gs,
                             int E, int n) {
  int i = blockIdx.x * 256 + threadIdx.x;
  if (i < E) atomicAdd(&counts[dst[i]], 1);
  if (i < n) {
    int b = batch[i];
    if (i == 0) {
      for (int g = 0; g <= b; ++g) gs[g] = 0;
    } else {
      int bp = batch[i - 1];
      for (int g = bp + 1; g <= b; ++g) gs[g] = i;
    }
    if (i == n - 1) {
      for (int g = b + 1; g <= NG; ++g) gs[g] = n;
    }
  }
}

// ---------------- 3-phase parallel exclusive scan (counts -> row_ptr) ----------------

__global__ __launch_bounds__(256) void scan1_kernel(const int* __restrict__ counts,
                                                    int* __restrict__ blocksum,
                                                    float* __restrict__ dinv, int n) {
  __shared__ int s[256];
  int tid = threadIdx.x;
  int i = blockIdx.x * 256 + tid;
  int c = (i < n) ? counts[i] : 0;
  if (i < n) dinv[i] = rsqrtf((float)(c + 1));
  s[tid] = c;
  __syncthreads();
#pragma unroll
  for (int off = 128; off > 0; off >>= 1) {
    if (tid < off) s[tid] += s[tid + off];
    __syncthreads();
  }
  if (tid == 0) blocksum[blockIdx.x] = s[0];
}

__global__ __launch_bounds__(1024) void scan2_kernel(int* __restrict__ blocksum, int nb) {
  __shared__ int s[1024];
  int tid = threadIdx.x;
  int v = (tid < nb) ? blocksum[tid] : 0;
  s[tid] = v;
  __syncthreads();
  for (int off = 1; off < 1024; off <<= 1) {
    int t = (tid >= off) ? s[tid - off] : 0;
    __syncthreads();
    s[tid] += t;
    __syncthreads();
  }
  if (tid < nb) blocksum[tid] = s[tid] - v;  // exclusive
}

__global__ __launch_bounds__(256) void scan3_kernel(const int* __restrict__ counts,
                                                    const int* __restrict__ blocksum,
                                                    int* __restrict__ row_ptr, int n) {
  __shared__ int s[256];
  int tid = threadIdx.x;
  int i = blockIdx.x * 256 + tid;
  int c = (i < n) ? counts[i] : 0;
  s[tid] = c;
  __syncthreads();
  for (int off = 1; off < 256; off <<= 1) {
    int t = (tid >= off) ? s[tid - off] : 0;
    __syncthreads();
    s[tid] += t;
    __syncthreads();
  }
  int base = blocksum[blockIdx.x];
  if (i < n) row_ptr[i] = base + s[tid] - c;
  if (i == n - 1) row_ptr[n] = base + s[tid];
}

__global__ void fill_kernel(const int* __restrict__ src, const int* __restrict__ dst,
                            const int* __restrict__ row_ptr, int* __restrict__ fill,
                            int* __restrict__ csr_src, int E) {
  int e = blockIdx.x * 256 + threadIdx.x;
  if (e >= E) return;
  int d = dst[e];
  int pos = row_ptr[d] + atomicAdd(&fill[d], 1);
  csr_src[pos] = src[e];
}

// ---------------- weight prep: W[k][200] fp32 -> WT_h/WT_l [224][KP] f16 ----------------

__global__ void wprep_kernel(const float* __restrict__ W, _Float16* __restrict__ WTh,
                             _Float16* __restrict__ WTl, int K, int KP) {
  int idx = blockIdx.x * 256 + threadIdx.x;
  if (idx >= 224 * KP) return;
  int col = idx / KP, k = idx % KP;
  float v = (col < HIDW && k < K) ? W[(long)k * HIDW + col] : 0.f;
  _Float16 h = (_Float16)v;
  WTh[idx] = h;
  WTl[idx] = (_Float16)(v - (float)h);
}

// ---------------- x f32 [n][128] -> dinv-scaled slice-major f16 [4][n][32] -------------

__global__ void cvt_kernel(const float* __restrict__ x, const float* __restrict__ dinv,
                           _Float16* __restrict__ g0, int n) {
  int t = blockIdx.x * 256 + threadIdx.x;
  if (t >= n * 32) return;
  int node = t >> 5, q = t & 31;
  float di = dinv[node];
  float4 v = *(const float4*)&x[(long)node * 128 + q * 4];
  half4_t r = {(_Float16)(di * v.x), (_Float16)(di * v.y),
               (_Float16)(di * v.z), (_Float16)(di * v.w)};
  ((half4_t*)g0)[((long)(q >> 3) * n + node) * 8 + (q & 7)] = r;
}

// ---------------- aggregation: z[i] = dinv[i] * (g[i] + sum_{s in N(i)} g[s]) ---------
// g tables are pre-scaled by dinv (fold), slice-major [NSLICE][n][32] f16.
// slot = blockIdx.x & 7 -> XCD; each XCD works one 2.56 MB L2-resident slice.
// wave = 1 node: 64 lanes = 8 edge-slots x 8 feature-quads -> no divergence,
// 8 gathers in flight; cross-slot reduce = 3 shfl_xor rounds. 4 nodes per wave.

template <int NSLICE>
__global__ __launch_bounds__(256) void agg_kernel(const _Float16* __restrict__ g,
                                                  const int* __restrict__ row_ptr,
                                                  const int* __restrict__ csr_src,
                                                  const float* __restrict__ dinv,
                                                  _Float16* __restrict__ out, int n) {
  int slot = blockIdx.x & 7;
  int nb = blockIdx.x >> 3;
  int wv = threadIdx.x >> 6;
  int lane = threadIdx.x & 63;
  int q = lane & 7;        // feature quad (half4)
  int es = lane >> 3;      // edge slot 0..7
  int slice, base;
  if (NSLICE == 7) {
    if (slot == 7) return;
    slice = slot;
    base = nb * 16;
  } else {  // NSLICE == 4
    slice = slot >> 1;
    base = (nb * 2 + (slot & 1)) * 16;
  }
  const half4_t* __restrict__ hp = (const half4_t*)g + (long)slice * n * 8;
  half4_t* __restrict__ op = (half4_t*)out + (long)slice * n * 8;

#pragma unroll
  for (int i = 0; i < 4; ++i) {
    int node = base + wv * 4 + i;
    if (node >= n) break;
    int e0 = row_ptr[node], e1 = row_ptr[node + 1];
    float ax = 0.f, ay = 0.f, az = 0.f, aw = 0.f;
    for (int e = e0 + es; e < e1; e += 8) {
      int s = csr_src[e];
      half4_t v = hp[s * 8 + q];
      ax += (float)v.x; ay += (float)v.y; az += (float)v.z; aw += (float)v.w;
    }
    // reduce across edge slots (lane bits 3..5)
#pragma unroll
    for (int m = 8; m < 64; m <<= 1) {
      ax += __shfl_xor(ax, m); ay += __shfl_xor(ay, m);
      az += __shfl_xor(az, m); aw += __shfl_xor(aw, m);
    }
    if (es == 0) {
      half4_t self = hp[node * 8 + q];
      float di = dinv[node];
      half4_t r = {(_Float16)(di * (ax + (float)self.x)),
                   (_Float16)(di * (ay + (float)self.y)),
                   (_Float16)(di * (az + (float)self.z)),
                   (_Float16)(di * (aw + (float)self.w))};
      __builtin_nontemporal_store(r, op + node * 8 + q);
    }
  }
}

// ---------------- MFMA GEMM, no LDS, no barriers; slice-major A and out -------------
// A: [KP/32][n][32] f16 (true aggregated features). out: [7][n][32] f16.
// MODE 1 = relu, MODE 2 = gated (A[row][col]*sigmoid(acc+bias), A==h3).
// DSCALE: multiply output by dinv[row] (fold for next agg layer).

template <int KP, int MODE, int DSCALE>
__global__ __launch_bounds__(256, 4) void mgemm_kernel(const _Float16* __restrict__ A,
                                                       const _Float16* __restrict__ WTh,
                                                       const _Float16* __restrict__ WTl,
                                                       const float* __restrict__ bias,
                                                       const float* __restrict__ dinv,
                                                       _Float16* __restrict__ out, int N) {
  int tid = threadIdx.x;
  int lane = tid & 63;
  int w = blockIdx.x * 4 + (tid >> 6);
  int wt = w >> 1;
  int wc = w & 1;
  int row0 = wt * 32;
  if (row0 >= N) return;
  int l15 = lane & 15;
  int lq = lane >> 4;

  const _Float16* __restrict__ pbh = WTh + (long)(wc * 112 + l15) * KP + lq * 8;
  const _Float16* __restrict__ pbl = WTl + (long)(wc * 112 + l15) * KP + lq * 8;

  floatx4 acc[2][7];
#pragma unroll
  for (int i = 0; i < 2; ++i)
#pragma unroll
    for (int j = 0; j < 7; ++j) acc[i][j] = (floatx4){0.f, 0.f, 0.f, 0.f};

#pragma unroll
  for (int k0 = 0; k0 < KP; k0 += 32) {
    const _Float16* as = A + ((long)(k0 >> 5) * N + row0 + l15) * 32 + lq * 8;
    half8_t a0 = *(const half8_t*)as;
    half8_t a1 = *(const half8_t*)(as + 16 * 32);
#pragma unroll
    for (int cf = 0; cf < 7; ++cf) {
      half8_t bh = *(const half8_t*)(pbh + (long)cf * 16 * KP + k0);
      acc[0][cf] = __builtin_amdgcn_mfma_f32_16x16x32_f16(a0, bh, acc[0][cf], 0, 0, 0);
      acc[1][cf] = __builtin_amdgcn_mfma_f32_16x16x32_f16(a1, bh, acc[1][cf], 0, 0, 0);
    }
#pragma unroll
    for (int cf = 0; cf < 7; ++cf) {
      half8_t bl = *(const half8_t*)(pbl + (long)cf * 16 * KP + k0);
      acc[0][cf] = __builtin_amdgcn_mfma_f32_16x16x32_f16(a0, bl, acc[0][cf], 0, 0, 0);
      acc[1][cf] = __builtin_amdgcn_mfma_f32_16x16x32_f16(a1, bl, acc[1][cf], 0, 0, 0);
    }
  }

#pragma unroll
  for (int cf = 0; cf < 7; ++cf) {
    int col = wc * 112 + cf * 16 + l15;
    float bs = (col < HIDW) ? bias[col] : 0.f;
    long obase = ((long)(col >> 5) * N) * 32 + (col & 31);
#pragma unroll
    for (int rf = 0; rf < 2; ++rf) {
      int rbase = row0 + rf * 16 + lq * 4;
#pragma unroll
      for (int j = 0; j < 4; ++j) {
        int row = rbase + j;
        float v = acc[rf][cf][j] + bs;
        if (MODE == 1) v = fmaxf(v, 0.f);
        if (MODE == 2) {
          float hv = (float)A[((long)(col >> 5) * N + row) * 32 + (col & 31)];
          v = hv * (1.f / (1.f + __expf(-v)));
        }
        if (DSCALE) v *= dinv[row];
        if (col >= HIDW) v = 0.f;  // keep pads zero
        out[obase + (long)row * 32] = (_Float16)v;
      }
    }
  }
}

// ---------------- mean pool partials over gated slice-major f16 ----------------

__global__ __launch_bounds__(256) void pool_partial_kernel(const _Float16* __restrict__ gated,
                                                           const int* __restrict__ gs,
                                                           float* __restrict__ partial, int n) {
  int g = blockIdx.x;
  int c = blockIdx.y;
  int f = threadIdx.x;
  int s = gs[g], e = gs[g + 1];
  int len = e - s;
  int chunk = (len + POOL_NC - 1) / POOL_NC;
  int i0 = s + c * chunk;
  int i1 = i0 + chunk; if (i1 > e) i1 = e;
  if (f < HIDW) {
    const _Float16* p = gated + ((long)(f >> 5) * n) * 32 + (f & 31);
    float acc = 0.f;
    for (int i = i0; i < i1; ++i) acc += (float)p[(long)i * 32];
    partial[(g * POOL_NC + c) * HIDW + f] = acc;
  }
}

// ---------------- classifier (fused pool-final): partial -> logits ----------------

__global__ void classifier_kernel(const float* __restrict__ partial,
                                  const int* __restrict__ gs,
                                  const float* __restrict__ Wc1, const float* __restrict__ bc1,
                                  const float* __restrict__ Wc2, const float* __restrict__ bc2,
                                  float* __restrict__ out) {
  int g = blockIdx.x;
  int tid = threadIdx.x;
  __shared__ float pg[HIDW];
  __shared__ float hid[100];
  if (tid < HIDW) {
    float acc = 0.f;
#pragma unroll
    for (int c = 0; c < POOL_NC; ++c) acc += partial[(g * POOL_NC + c) * HIDW + tid];
    float cnt = fmaxf((float)(gs[g + 1] - gs[g]), 1.f);
    pg[tid] = acc / cnt;
  }
  __syncthreads();
  if (tid < 100) {
    float a = bc1[tid];
    for (int k = 0; k < HIDW; ++k) a = fmaf(pg[k], Wc1[k * 100 + tid], a);
    hid[tid] = fmaxf(a, 0.f);
  }
  __syncthreads();
  if (tid < 2) {
    float a = bc2[tid];
    for (int k = 0; k < 100; ++k) a = fmaf(hid[k], Wc2[k * 2 + tid], a);
    out[g * 2 + tid] = a;
  }
}

// ---------------- launch ----------------

extern "C" void kernel_launch(void* const* d_in, const int* in_sizes, int n_in,
                              void* d_out, int out_size, void* d_ws, size_t ws_size,
                              hipStream_t stream) {
  const float* x    = (const float*)d_in[0];
  const int*   ei   = (const int*)d_in[1];
  const int*   batch= (const int*)d_in[2];
  const float* W1 = (const float*)d_in[3];  const float* b1 = (const float*)d_in[4];
  const float* W2 = (const float*)d_in[5];  const float* b2 = (const float*)d_in[6];
  const float* W3 = (const float*)d_in[7];  const float* b3 = (const float*)d_in[8];
  const float* Wg = (const float*)d_in[9];  const float* bg = (const float*)d_in[10];
  const float* Wc1= (const float*)d_in[11]; const float* bc1= (const float*)d_in[12];
  const float* Wc2= (const float*)d_in[13]; const float* bc2= (const float*)d_in[14];
  float* out = (float*)d_out;

  const int n = in_sizes[0] / DIN;     // 40000
  const int E = in_sizes[1] / 2;       // 640000
  const int* src = ei;
  const int* dst = ei + E;
  const int nb256 = (n + 255) / 256;   // 157 scan blocks

  // workspace carve-up (all segments 16B-aligned)
  int* counts   = (int*)d_ws;               // n
  int* fill     = counts + n;               // n
  int* row_ptr  = fill + n;                 // n+4
  int* gs       = row_ptr + (n + 4);        // 68
  int* blocksum = gs + 68;                  // 1024
  float* dinv   = (float*)(blocksum + 1024);// n
  int* csr_src  = (int*)(dinv + n);         // E
  float* partial= (float*)(csr_src + E);    // 64*8*200
  _Float16* wt1h = (_Float16*)(partial + NG * POOL_NC * HIDW);  // 224*128
  _Float16* wt1l = wt1h + 224 * 128;
  _Float16* wt2h = wt1l + 224 * 128;
  _Float16* wt2l = wt2h + 224 * KPAD;
  _Float16* wt3h = wt2l + 224 * KPAD;
  _Float16* wt3l = wt3h + 224 * KPAD;
  _Float16* wtgh = wt3l + 224 * KPAD;
  _Float16* wtgl = wtgh + 224 * KPAD;
  _Float16* xh   = wtgl + 224 * KPAD;           // [4][n][32] f16 (dinv-scaled)
  _Float16* bufA = xh + (long)n * DIN;          // [7][n][32] f16
  _Float16* bufB = bufA + (long)n * KPAD;       // [7][n][32] f16

  hipMemsetAsync(counts, 0, (size_t)2 * n * sizeof(int), stream);  // counts + fill

  // weight prep (independent of graph build)
  wprep_kernel<<<(224 * 128 + 255) / 256, 256, 0, stream>>>(W1, wt1h, wt1l, 128, 128);
  wprep_kernel<<<(224 * KPAD + 255) / 256, 256, 0, stream>>>(W2, wt2h, wt2l, 200, KPAD);
  wprep_kernel<<<(224 * KPAD + 255) / 256, 256, 0, stream>>>(W3, wt3h, wt3l, 200, KPAD);
  wprep_kernel<<<(224 * KPAD + 255) / 256, 256, 0, stream>>>(Wg, wtgh, wtgl, 200, KPAD);

  int eb = (E + 255) / 256;
  build_kernel<<<eb, 256, 0, stream>>>(dst, counts, batch, gs, E, n);
  scan1_kernel<<<nb256, 256, 0, stream>>>(counts, blocksum, dinv, n);
  // cvt needs dinv (from scan1): g0 = dinv * x
  cvt_kernel<<<(n * 32 + 255) / 256, 256, 0, stream>>>(x, dinv, xh, n);
  scan2_kernel<<<1, 1024, 0, stream>>>(blocksum, nb256);
  scan3_kernel<<<nb256, 256, 0, stream>>>(counts, blocksum, row_ptr, n);
  fill_kernel<<<eb, 256, 0, stream>>>(src, dst, row_ptr, fill, csr_src, E);

  int ag7 = 8 * ((n + 15) / 16);        // 7-slice agg grid (slot 7 idles)
  int ag4 = 8 * ((n + 31) / 32);        // 4-slice agg grid
  int gb = ((n / 32) * 2 + 3) / 4;      // gemm: 2500 waves -> 625 blocks

  // layer 1: z1 = agg(g0); h1s = dinv*relu(z1@W1+b1)
  agg_kernel<4><<<ag4, 256, 0, stream>>>(xh, row_ptr, csr_src, dinv, bufA, n);
  mgemm_kernel<DIN, 1, 1><<<gb, 256, 0, stream>>>(bufA, wt1h, wt1l, b1, dinv, bufB, n);
  // layer 2
  agg_kernel<7><<<ag7, 256, 0, stream>>>(bufB, row_ptr, csr_src, dinv, bufA, n);
  mgemm_kernel<KPAD, 1, 1><<<gb, 256, 0, stream>>>(bufA, wt2h, wt2l, b2, dinv, bufB, n);
  // layer 3 (h3 unscaled: feeds gate + pool, not another agg)
  agg_kernel<7><<<ag7, 256, 0, stream>>>(bufB, row_ptr, csr_src, dinv, bufA, n);
  mgemm_kernel<KPAD, 1, 0><<<gb, 256, 0, stream>>>(bufA, wt3h, wt3l, b3, dinv, bufB, n);
  // gate + apply: bufA = h3 * sigmoid(h3 @ Wg + bg)
  mgemm_kernel<KPAD, 2, 0><<<gb, 256, 0, stream>>>(bufB, wtgh, wtgl, bg, dinv, bufA, n);
  // mean-pool partials + fused pool-final/classifier
  dim3 pgrid(NG, POOL_NC);
  pool_partial_kernel<<<pgrid, 256, 0, stream>>>(bufA, gs, partial, n);
  classifier_kernel<<<NG, 256, 0, stream>>>(partial, gs, Wc1, bc1, Wc2, bc2, out);
}

// Round 9
// 390.543 us; speedup vs baseline: 1.1899x; 1.1899x over previous
//
#include <hip/hip_runtime.h>

#define NG 64
#define HIDW 200
#define DIN 128
#define KPAD 224
#define POOL_NC 8

typedef _Float16 half4_t __attribute__((ext_vector_type(4)));
typedef _Float16 half8_t __attribute__((ext_vector_type(8)));
typedef float floatx4 __attribute__((ext_vector_type(4)));

// ---------------- build: degree count + graph-start table (fused) ----------------

__global__ void build_kernel(const int* __restrict__ dst, int* __restrict__ counts,
                             const int* __restrict__ batch, int* __restrict__ gs,
                             int E, int n) {
  int i = blockIdx.x * 256 + threadIdx.x;
  if (i < E) atomicAdd(&counts[dst[i]], 1);
  if (i < n) {
    int b = batch[i];
    if (i == 0) {
      for (int g = 0; g <= b; ++g) gs[g] = 0;
    } else {
      int bp = batch[i - 1];
      for (int g = bp + 1; g <= b; ++g) gs[g] = i;
    }
    if (i == n - 1) {
      for (int g = b + 1; g <= NG; ++g) gs[g] = n;
    }
  }
}

// ---------------- 3-phase parallel exclusive scan (counts -> row_ptr) ----------------

__global__ __launch_bounds__(256) void scan1_kernel(const int* __restrict__ counts,
                                                    int* __restrict__ blocksum,
                                                    float* __restrict__ dinv, int n) {
  __shared__ int s[256];
  int tid = threadIdx.x;
  int i = blockIdx.x * 256 + tid;
  int c = (i < n) ? counts[i] : 0;
  if (i < n) dinv[i] = rsqrtf((float)(c + 1));
  s[tid] = c;
  __syncthreads();
#pragma unroll
  for (int off = 128; off > 0; off >>= 1) {
    if (tid < off) s[tid] += s[tid + off];
    __syncthreads();
  }
  if (tid == 0) blocksum[blockIdx.x] = s[0];
}

__global__ __launch_bounds__(1024) void scan2_kernel(int* __restrict__ blocksum, int nb) {
  __shared__ int s[1024];
  int tid = threadIdx.x;
  int v = (tid < nb) ? blocksum[tid] : 0;
  s[tid] = v;
  __syncthreads();
  for (int off = 1; off < 1024; off <<= 1) {
    int t = (tid >= off) ? s[tid - off] : 0;
    __syncthreads();
    s[tid] += t;
    __syncthreads();
  }
  if (tid < nb) blocksum[tid] = s[tid] - v;  // exclusive
}

__global__ __launch_bounds__(256) void scan3_kernel(const int* __restrict__ counts,
                                                    const int* __restrict__ blocksum,
                                                    int* __restrict__ row_ptr, int n) {
  __shared__ int s[256];
  int tid = threadIdx.x;
  int i = blockIdx.x * 256 + tid;
  int c = (i < n) ? counts[i] : 0;
  s[tid] = c;
  __syncthreads();
  for (int off = 1; off < 256; off <<= 1) {
    int t = (tid >= off) ? s[tid - off] : 0;
    __syncthreads();
    s[tid] += t;
    __syncthreads();
  }
  int base = blocksum[blockIdx.x];
  if (i < n) row_ptr[i] = base + s[tid] - c;
  if (i == n - 1) row_ptr[n] = base + s[tid];
}

__global__ void fill_kernel(const int* __restrict__ src, const int* __restrict__ dst,
                            const int* __restrict__ row_ptr, int* __restrict__ fill,
                            int* __restrict__ csr_src, int E) {
  int e = blockIdx.x * 256 + threadIdx.x;
  if (e >= E) return;
  int d = dst[e];
  int pos = row_ptr[d] + atomicAdd(&fill[d], 1);
  csr_src[pos] = src[e];
}

// ---------------- weight prep: W[k][200] fp32 -> WT_h/WT_l [224][KP] f16 ----------------

__global__ void wprep_kernel(const float* __restrict__ W, _Float16* __restrict__ WTh,
                             _Float16* __restrict__ WTl, int K, int KP) {
  int idx = blockIdx.x * 256 + threadIdx.x;
  if (idx >= 224 * KP) return;
  int col = idx / KP, k = idx % KP;
  float v = (col < HIDW && k < K) ? W[(long)k * HIDW + col] : 0.f;
  _Float16 h = (_Float16)v;
  WTh[idx] = h;
  WTl[idx] = (_Float16)(v - (float)h);
}

// ---------------- x f32 [n][128] -> dinv-scaled row-major f16 [n][128] ----------------

__global__ void cvt_kernel(const float* __restrict__ x, const float* __restrict__ dinv,
                           _Float16* __restrict__ g0, int n) {
  int t = blockIdx.x * 256 + threadIdx.x;
  if (t >= n * 32) return;
  int node = t >> 5, q = t & 31;
  float di = dinv[node];
  float4 v = *(const float4*)&x[(long)node * 128 + q * 4];
  half4_t r = {(_Float16)(di * v.x), (_Float16)(di * v.y),
               (_Float16)(di * v.z), (_Float16)(di * v.w)};
  ((half4_t*)g0)[(long)node * 32 + q] = r;
}

// ---------------- aggregation: z[i] = dinv[i] * (g[i] + sum_{s in N(i)} g[s]) ---------
// g pre-scaled by dinv (fold: no per-edge weight). Row-major [n][C*4] f16.
// wave per node, lanes 0..C-1 own half4 chunks; per edge: 1 idx + 1 448B gather.
// unroll 8 main + 4-step mid-tail (keeps >=4 gathers in flight through the tail).

template <int C>
__global__ __launch_bounds__(256) void agg_kernel(const _Float16* __restrict__ g,
                                                  const int* __restrict__ row_ptr,
                                                  const int* __restrict__ csr_src,
                                                  const float* __restrict__ dinv,
                                                  _Float16* __restrict__ out, int n) {
  int node = blockIdx.x * 4 + (threadIdx.x >> 6);
  int lane = threadIdx.x & 63;
  if (node >= n || lane >= C) return;
  const half4_t* __restrict__ hp = (const half4_t*)g;
  int e0 = row_ptr[node], e1 = row_ptr[node + 1];
  half4_t self = hp[(long)node * C + lane];
  float ax = (float)self.x, ay = (float)self.y;
  float az = (float)self.z, aw = (float)self.w;

  int e = e0;
  for (; e + 8 <= e1; e += 8) {
    int s0 = csr_src[e + 0], s1 = csr_src[e + 1], s2 = csr_src[e + 2], s3 = csr_src[e + 3];
    int s4 = csr_src[e + 4], s5 = csr_src[e + 5], s6 = csr_src[e + 6], s7 = csr_src[e + 7];
    half4_t v0 = hp[(long)s0 * C + lane];
    half4_t v1 = hp[(long)s1 * C + lane];
    half4_t v2 = hp[(long)s2 * C + lane];
    half4_t v3 = hp[(long)s3 * C + lane];
    half4_t v4 = hp[(long)s4 * C + lane];
    half4_t v5 = hp[(long)s5 * C + lane];
    half4_t v6 = hp[(long)s6 * C + lane];
    half4_t v7 = hp[(long)s7 * C + lane];
    ax += (float)v0.x + (float)v1.x + (float)v2.x + (float)v3.x
        + (float)v4.x + (float)v5.x + (float)v6.x + (float)v7.x;
    ay += (float)v0.y + (float)v1.y + (float)v2.y + (float)v3.y
        + (float)v4.y + (float)v5.y + (float)v6.y + (float)v7.y;
    az += (float)v0.z + (float)v1.z + (float)v2.z + (float)v3.z
        + (float)v4.z + (float)v5.z + (float)v6.z + (float)v7.z;
    aw += (float)v0.w + (float)v1.w + (float)v2.w + (float)v3.w
        + (float)v4.w + (float)v5.w + (float)v6.w + (float)v7.w;
  }
  if (e + 4 <= e1) {
    int s0 = csr_src[e + 0], s1 = csr_src[e + 1], s2 = csr_src[e + 2], s3 = csr_src[e + 3];
    half4_t v0 = hp[(long)s0 * C + lane];
    half4_t v1 = hp[(long)s1 * C + lane];
    half4_t v2 = hp[(long)s2 * C + lane];
    half4_t v3 = hp[(long)s3 * C + lane];
    ax += (float)v0.x + (float)v1.x + (float)v2.x + (float)v3.x;
    ay += (float)v0.y + (float)v1.y + (float)v2.y + (float)v3.y;
    az += (float)v0.z + (float)v1.z + (float)v2.z + (float)v3.z;
    aw += (float)v0.w + (float)v1.w + (float)v2.w + (float)v3.w;
    e += 4;
  }
  for (; e < e1; ++e) {
    int s = csr_src[e];
    half4_t v = hp[(long)s * C + lane];
    ax += (float)v.x; ay += (float)v.y; az += (float)v.z; aw += (float)v.w;
  }
  float di = dinv[node];
  half4_t r = {(_Float16)(di * ax), (_Float16)(di * ay),
               (_Float16)(di * az), (_Float16)(di * aw)};
  ((half4_t*)out)[(long)node * C + lane] = r;
}

// ---------------- MFMA GEMM, no LDS, no barriers; row-major A and out ----------------
// A: [N][KP] f16. out: [N][224] f16 (pads zeroed). W: [224][KP] f16 split Wh+Wl.
// Block's 4 waves share wc (same B half-panel -> L1 reuse), span 4 row tiles.
// MODE 1 = relu, 2 = gated (A[row][col]*sigmoid(acc+bias), A==h3).
// DSCALE: multiply output by dinv[row] (fold for next agg layer).

template <int KP, int MODE, int DSCALE>
__global__ __launch_bounds__(256, 4) void mgemm_kernel(const _Float16* __restrict__ A,
                                                       const _Float16* __restrict__ WTh,
                                                       const _Float16* __restrict__ WTl,
                                                       const float* __restrict__ bias,
                                                       const float* __restrict__ dinv,
                                                       _Float16* __restrict__ out, int N) {
  int tid = threadIdx.x;
  int lane = tid & 63;
  int wc = blockIdx.x & 1;                       // B half shared by all 4 waves
  int wt = (blockIdx.x >> 1) * 4 + (tid >> 6);   // row tile
  int row0 = wt * 32;
  if (row0 >= N) return;
  int l15 = lane & 15;
  int lq = lane >> 4;

  const _Float16* __restrict__ pbh = WTh + (long)(wc * 112 + l15) * KP + lq * 8;
  const _Float16* __restrict__ pbl = WTl + (long)(wc * 112 + l15) * KP + lq * 8;
  const _Float16* __restrict__ pa0 = A + (long)(row0 + l15) * KP + lq * 8;
  const _Float16* __restrict__ pa1 = pa0 + 16 * KP;

  floatx4 acc[2][7];
#pragma unroll
  for (int i = 0; i < 2; ++i)
#pragma unroll
    for (int j = 0; j < 7; ++j) acc[i][j] = (floatx4){0.f, 0.f, 0.f, 0.f};

#pragma unroll
  for (int k0 = 0; k0 < KP; k0 += 32) {
    half8_t a0 = *(const half8_t*)(pa0 + k0);
    half8_t a1 = *(const half8_t*)(pa1 + k0);
#pragma unroll
    for (int cf = 0; cf < 7; ++cf) {
      half8_t bh = *(const half8_t*)(pbh + (long)cf * 16 * KP + k0);
      acc[0][cf] = __builtin_amdgcn_mfma_f32_16x16x32_f16(a0, bh, acc[0][cf], 0, 0, 0);
      acc[1][cf] = __builtin_amdgcn_mfma_f32_16x16x32_f16(a1, bh, acc[1][cf], 0, 0, 0);
    }
#pragma unroll
    for (int cf = 0; cf < 7; ++cf) {
      half8_t bl = *(const half8_t*)(pbl + (long)cf * 16 * KP + k0);
      acc[0][cf] = __builtin_amdgcn_mfma_f32_16x16x32_f16(a0, bl, acc[0][cf], 0, 0, 0);
      acc[1][cf] = __builtin_amdgcn_mfma_f32_16x16x32_f16(a1, bl, acc[1][cf], 0, 0, 0);
    }
  }

#pragma unroll
  for (int cf = 0; cf < 7; ++cf) {
    int col = wc * 112 + cf * 16 + l15;
    float bs = (col < HIDW) ? bias[col] : 0.f;
#pragma unroll
    for (int rf = 0; rf < 2; ++rf) {
      int rbase = row0 + rf * 16 + lq * 4;
#pragma unroll
      for (int j = 0; j < 4; ++j) {
        int row = rbase + j;
        float v = acc[rf][cf][j] + bs;
        if (MODE == 1) v = fmaxf(v, 0.f);
        if (MODE == 2) {
          float hv = (float)A[(long)row * KP + col];
          v = hv * (1.f / (1.f + __expf(-v)));
        }
        if (DSCALE) v *= dinv[row];
        if (col >= HIDW) v = 0.f;  // keep pads zero
        out[(long)row * KPAD + col] = (_Float16)v;
      }
    }
  }
}

// ---------------- mean pool partials over gated row-major f16 ----------------

__global__ __launch_bounds__(256) void pool_partial_kernel(const _Float16* __restrict__ gated,
                                                           const int* __restrict__ gs,
                                                           float* __restrict__ partial, int n) {
  int g = blockIdx.x;
  int c = blockIdx.y;
  int f = threadIdx.x;
  int s = gs[g], e = gs[g + 1];
  int len = e - s;
  int chunk = (len + POOL_NC - 1) / POOL_NC;
  int i0 = s + c * chunk;
  int i1 = i0 + chunk; if (i1 > e) i1 = e;
  if (f < HIDW) {
    float acc = 0.f;
    for (int i = i0; i < i1; ++i) acc += (float)gated[(long)i * KPAD + f];
    partial[(g * POOL_NC + c) * HIDW + f] = acc;
  }
}

// ---------------- classifier (fused pool-final): partial -> logits ----------------

__global__ void classifier_kernel(const float* __restrict__ partial,
                                  const int* __restrict__ gs,
                                  const float* __restrict__ Wc1, const float* __restrict__ bc1,
                                  const float* __restrict__ Wc2, const float* __restrict__ bc2,
                                  float* __restrict__ out) {
  int g = blockIdx.x;
  int tid = threadIdx.x;
  __shared__ float pg[HIDW];
  __shared__ float hid[100];
  if (tid < HIDW) {
    float acc = 0.f;
#pragma unroll
    for (int c = 0; c < POOL_NC; ++c) acc += partial[(g * POOL_NC + c) * HIDW + tid];
    float cnt = fmaxf((float)(gs[g + 1] - gs[g]), 1.f);
    pg[tid] = acc / cnt;
  }
  __syncthreads();
  if (tid < 100) {
    float a = bc1[tid];
    for (int k = 0; k < HIDW; ++k) a = fmaf(pg[k], Wc1[k * 100 + tid], a);
    hid[tid] = fmaxf(a, 0.f);
  }
  __syncthreads();
  if (tid < 2) {
    float a = bc2[tid];
    for (int k = 0; k < 100; ++k) a = fmaf(hid[k], Wc2[k * 2 + tid], a);
    out[g * 2 + tid] = a;
  }
}

// ---------------- launch ----------------

extern "C" void kernel_launch(void* const* d_in, const int* in_sizes, int n_in,
                              void* d_out, int out_size, void* d_ws, size_t ws_size,
                              hipStream_t stream) {
  const float* x    = (const float*)d_in[0];
  const int*   ei   = (const int*)d_in[1];
  const int*   batch= (const int*)d_in[2];
  const float* W1 = (const float*)d_in[3];  const float* b1 = (const float*)d_in[4];
  const float* W2 = (const float*)d_in[5];  const float* b2 = (const float*)d_in[6];
  const float* W3 = (const float*)d_in[7];  const float* b3 = (const float*)d_in[8];
  const float* Wg = (const float*)d_in[9];  const float* bg = (const float*)d_in[10];
  const float* Wc1= (const float*)d_in[11]; const float* bc1= (const float*)d_in[12];
  const float* Wc2= (const float*)d_in[13]; const float* bc2= (const float*)d_in[14];
  float* out = (float*)d_out;

  const int n = in_sizes[0] / DIN;     // 40000
  const int E = in_sizes[1] / 2;       // 640000
  const int* src = ei;
  const int* dst = ei + E;
  const int nb256 = (n + 255) / 256;   // 157 scan blocks

  // workspace carve-up (all segments 16B-aligned)
  int* counts   = (int*)d_ws;               // n
  int* fill     = counts + n;               // n
  int* row_ptr  = fill + n;                 // n+4
  int* gs       = row_ptr + (n + 4);        // 68
  int* blocksum = gs + 68;                  // 1024
  float* dinv   = (float*)(blocksum + 1024);// n
  int* csr_src  = (int*)(dinv + n);         // E
  float* partial= (float*)(csr_src + E);    // 64*8*200
  _Float16* wt1h = (_Float16*)(partial + NG * POOL_NC * HIDW);  // 224*128
  _Float16* wt1l = wt1h + 224 * 128;
  _Float16* wt2h = wt1l + 224 * 128;
  _Float16* wt2l = wt2h + 224 * KPAD;
  _Float16* wt3h = wt2l + 224 * KPAD;
  _Float16* wt3l = wt3h + 224 * KPAD;
  _Float16* wtgh = wt3l + 224 * KPAD;
  _Float16* wtgl = wtgh + 224 * KPAD;
  _Float16* xh   = wtgl + 224 * KPAD;           // [n][128] f16 (dinv-scaled)
  _Float16* bufA = xh + (long)n * DIN;          // [n][224] f16
  _Float16* bufB = bufA + (long)n * KPAD;       // [n][224] f16

  hipMemsetAsync(counts, 0, (size_t)2 * n * sizeof(int), stream);  // counts + fill

  // weight prep (independent of graph build)
  wprep_kernel<<<(224 * 128 + 255) / 256, 256, 0, stream>>>(W1, wt1h, wt1l, 128, 128);
  wprep_kernel<<<(224 * KPAD + 255) / 256, 256, 0, stream>>>(W2, wt2h, wt2l, 200, KPAD);
  wprep_kernel<<<(224 * KPAD + 255) / 256, 256, 0, stream>>>(W3, wt3h, wt3l, 200, KPAD);
  wprep_kernel<<<(224 * KPAD + 255) / 256, 256, 0, stream>>>(Wg, wtgh, wtgl, 200, KPAD);

  int eb = (E + 255) / 256;
  build_kernel<<<eb, 256, 0, stream>>>(dst, counts, batch, gs, E, n);
  scan1_kernel<<<nb256, 256, 0, stream>>>(counts, blocksum, dinv, n);
  // cvt needs dinv (from scan1): g0 = dinv * x
  cvt_kernel<<<(n * 32 + 255) / 256, 256, 0, stream>>>(x, dinv, xh, n);
  scan2_kernel<<<1, 1024, 0, stream>>>(blocksum, nb256);
  scan3_kernel<<<nb256, 256, 0, stream>>>(counts, blocksum, row_ptr, n);
  fill_kernel<<<eb, 256, 0, stream>>>(src, dst, row_ptr, fill, csr_src, E);

  int ab = (n + 3) / 4;                 // agg blocks (wave per node)
  int gb = ((n / 32 + 3) / 4) * 2;      // gemm: 1250 row-tiles / 4 waves * 2 wc = 626

  // layer 1: z1 = agg(g0); bufB = dinv*relu(z1@W1+b1)
  agg_kernel<32><<<ab, 256, 0, stream>>>(xh, row_ptr, csr_src, dinv, bufA, n);
  mgemm_kernel<DIN, 1, 1><<<gb, 256, 0, stream>>>(bufA, wt1h, wt1l, b1, dinv, bufB, n);
  // layer 2
  agg_kernel<56><<<ab, 256, 0, stream>>>(bufB, row_ptr, csr_src, dinv, bufA, n);
  mgemm_kernel<KPAD, 1, 1><<<gb, 256, 0, stream>>>(bufA, wt2h, wt2l, b2, dinv, bufB, n);
  // layer 3 (h3 unscaled: feeds gate + pool, not another agg)
  agg_kernel<56><<<ab, 256, 0, stream>>>(bufB, row_ptr, csr_src, dinv, bufA, n);
  mgemm_kernel<KPAD, 1, 0><<<gb, 256, 0, stream>>>(bufA, wt3h, wt3l, b3, dinv, bufB, n);
  // gate + apply: bufA = h3 * sigmoid(h3 @ Wg + bg)
  mgemm_kernel<KPAD, 2, 0><<<gb, 256, 0, stream>>>(bufB, wtgh, wtgl, bg, dinv, bufA, n);
  // mean-pool partials + fused pool-final/classifier
  dim3 pgrid(NG, POOL_NC);
  pool_partial_kernel<<<pgrid, 256, 0, stream>>>(bufA, gs, partial, n);
  classifier_kernel<<<NG, 256, 0, stream>>>(partial, gs, Wc1, bc1, Wc2, bc2, out);
}